// Round 1
// 931.586 us; speedup vs baseline: 1.0086x; 1.0086x over previous
//
#include <hip/hip_runtime.h>
#include <hip/hip_bf16.h>
#include <math.h>

typedef unsigned short ushort_t;
typedef __bf16 bf16x8 __attribute__((ext_vector_type(8)));
typedef float floatx4 __attribute__((ext_vector_type(4)));
typedef float floatx8 __attribute__((ext_vector_type(8)));

#define NEG_BIG -1000000000.0f

__device__ __forceinline__ float b2f(ushort_t u) {
  union { unsigned int i; float f; } v;
  v.i = ((unsigned int)u) << 16;
  return v.f;
}
__device__ __forceinline__ ushort_t f2b(float f) {
  union { float f; unsigned int i; } v;
  v.f = f;
  unsigned int r = v.i + 0x7fffu + ((v.i >> 16) & 1u);  // round-nearest-even
  return (ushort_t)(r >> 16);
}

__device__ __forceinline__ float loadC(const float* p) { return *p; }
__device__ __forceinline__ float loadC(const ushort_t* p) { return b2f(*p); }
__device__ __forceinline__ void storeC(float* p, float v) { *p = v; }
__device__ __forceinline__ void storeC(ushort_t* p, float v) { *p = f2b(v); }

// ---------------------------------------------------------------------------
// Weight transpose + fp32->bf16 convert: Wt[512][4096] bf16.
// Rows 0..255 = w_kv columns, rows 256..511 = w_gate columns.
// ---------------------------------------------------------------------------
__global__ __launch_bounds__(256) void transpose_w_kernel(
    const float* __restrict__ w_kv, const float* __restrict__ w_gate,
    ushort_t* __restrict__ Wt) {
  __shared__ float tile[64][65];   // +1 pad: conflict-free transposed read
  const int K0 = blockIdx.x * 64;  // grid.x = 64  (K = 4096)
  const int N0c = blockIdx.y * 64; // grid.y = 8   (Ncat = 512)
  const float* src = (N0c < 256) ? w_kv : w_gate;
  const int N0 = N0c & 255;
  const int t = threadIdx.x;
#pragma unroll
  for (int i = 0; i < 16; ++i) {
    int l = t + 256 * i;
    int r = l >> 6, c = l & 63;
    tile[r][c] = src[(size_t)(K0 + r) * 256 + N0 + c];  // coalesced in c
  }
  __syncthreads();
#pragma unroll
  for (int i = 0; i < 16; ++i) {
    int l = t + 256 * i;
    int r = l >> 6, c = l & 63;
    Wt[(size_t)(N0c + r) * 4096 + K0 + c] = f2b(tile[c][r]);  // coalesced in c
  }
}

// ---------------------------------------------------------------------------
// GEMM: C[32768][512] = hidden_f32[32768][4096] @ Wt^T  (Wt is [512][4096] bf16)
// 128x128 tile, BK=64, 4 waves, double-buffered LDS with 1-tile prefetch
// (minimal 2-phase: issue next-tile loads BEFORE current-tile compute, single
// vmcnt-drain + barrier per K-step -> HBM latency hides under MFMA).
// LDS tiles XOR-swizzled (chunk16B ^= row&7): kills the 16-way ds_read_b128
// bank conflict of the 128B row stride. B is staged via global_load_lds with
// INVERSE-swizzled global source (linear LDS dest, rule 21 / m173 pattern).
// XCD-bijective block swizzle groups the 4 n-tiles of an m-tile on one XCD.
// ---------------------------------------------------------------------------
template <typename CT>
__global__ __launch_bounds__(256, 2) void gemm_kernel(
    const float* __restrict__ A,      // [32768][4096] fp32
    const ushort_t* __restrict__ Bt,  // [512][4096] bf16
    CT* __restrict__ C) {             // [32768][512]
  constexpr int K = 4096;
  __shared__ __align__(16) ushort_t As[2][128 * 64];  // 2 x 16 KiB
  __shared__ __align__(16) ushort_t Bs[2][128 * 64];  // 2 x 16 KiB

  // XCD-aware bijective swizzle: nwg=1024 divisible by 8 -> XCD x gets the
  // contiguous o-range [x*128, x*128+128). nt stays fast-varying so the 4
  // blocks sharing an m-tile are adjacent (concurrent) on one XCD -> A-slice
  // fetched once into that XCD's L2.
  const int bid = blockIdx.x;
  const int o = (bid & 7) * 128 + (bid >> 3);
  const int mt = o >> 2;           // 256 m-tiles
  const int nt = o & 3;            // 4 n-tiles
  const int m0 = mt * 128, n0 = nt * 128;

  const int tid = threadIdx.x;
  const int w = tid >> 6, lane = tid & 63;
  const int wm = w >> 1, wn = w & 1;   // 2x2 wave grid, 64x64 each
  const int q = lane >> 4, sid = lane & 15;
  // B staging: lane covers (row-sub lane>>3, k-chunk lane&7) of an 8-row chunk.
  // LDS dest is linear; fetch the inverse-swizzled global chunk so LDS slot
  // (row, c) holds global chunk c ^ (row&7).
  const int bsr = lane >> 3;                      // row within 8-row chunk
  const int bsc = ((lane & 7) ^ bsr) * 8;         // swizzled global k-offset
  // A staging (reg-staged fp32->bf16): write to swizzled LDS slot directly.
  const int ar = tid >> 3;                        // 0..31 row within pass
  const int aca = tid & 7;                        // global k-chunk 0..7
  const int acs = (aca ^ (ar & 7)) * 8;           // swizzled LDS k-offset

  floatx4 acc[4][4];
#pragma unroll
  for (int i = 0; i < 4; ++i)
#pragma unroll
    for (int j = 0; j < 4; ++j) acc[i][j] = (floatx4)0.0f;

#define STAGE_B(BUF, KT)                                                      \
  _Pragma("unroll")                                                           \
  for (int i = 0; i < 4; ++i) {                                               \
    const int chunk = i * 4 + w;                                              \
    const int row = chunk * 8 + bsr;                                          \
    const ushort_t* g = Bt + (size_t)(n0 + row) * K + (KT) + bsc;             \
    __builtin_amdgcn_global_load_lds(                                         \
        (const __attribute__((address_space(1))) void*)g,                     \
        (__attribute__((address_space(3))) void*)(&Bs[BUF][chunk * 512]), 16, \
        0, 0);                                                                \
  }

#define LOAD_A(KT, FREG)                                                      \
  _Pragma("unroll")                                                           \
  for (int p = 0; p < 4; ++p) {                                               \
    const int row = p * 32 + ar;                                              \
    FREG[p] = *(const floatx8*)(A + (size_t)(m0 + row) * K + (KT) + aca * 8); \
  }

#define WRITE_A(BUF, FREG)                                                    \
  _Pragma("unroll")                                                           \
  for (int p = 0; p < 4; ++p) {                                               \
    const int row = p * 32 + ar;                                              \
    *(bf16x8*)(&As[BUF][row * 64 + acs]) =                                    \
        __builtin_convertvector(FREG[p], bf16x8);                             \
  }

#define COMPUTE_TILE(BUF)                                                     \
  _Pragma("unroll")                                                           \
  for (int ks = 0; ks < 64; ks += 32) {                                       \
    const int kc = ks >> 3; /* 0 or 4 */                                      \
    bf16x8 af[4], bfr[4];                                                     \
    _Pragma("unroll")                                                         \
    for (int i = 0; i < 4; ++i) {                                             \
      const int ra = wm * 64 + i * 16 + sid;                                  \
      af[i] =                                                                 \
          *(const bf16x8*)(&As[BUF][ra * 64 + ((kc + q) ^ (sid & 7)) * 8]);   \
    }                                                                         \
    _Pragma("unroll")                                                         \
    for (int j2 = 0; j2 < 4; ++j2) {                                          \
      const int rb = wn * 64 + j2 * 16 + sid;                                 \
      bfr[j2] =                                                               \
          *(const bf16x8*)(&Bs[BUF][rb * 64 + ((kc + q) ^ (sid & 7)) * 8]);   \
    }                                                                         \
    _Pragma("unroll")                                                         \
    for (int i = 0; i < 4; ++i)                                               \
      _Pragma("unroll")                                                       \
      for (int j2 = 0; j2 < 4; ++j2)                                          \
        acc[i][j2] = __builtin_amdgcn_mfma_f32_16x16x32_bf16(                 \
            af[i], bfr[j2], acc[i][j2], 0, 0, 0);                             \
  }

  // ---- prologue: stage tile kt=0 into buffer 0
  {
    STAGE_B(0, 0)
    floatx8 f[4];
    LOAD_A(0, f)
    WRITE_A(0, f)
  }
  __syncthreads();

  int cur = 0;
  for (int kt = 64; kt < K; kt += 64) {
    // issue next-tile loads first: A -> regs, B -> LDS[cur^1] (async DMA)
    floatx8 f[4];
    LOAD_A(kt, f)
    STAGE_B(cur ^ 1, kt)
    // compute current tile while loads are in flight
    COMPUTE_TILE(cur)
    // convert + write prefetched A (compiler inserts the vmcnt wait here)
    WRITE_A(cur ^ 1, f)
    __syncthreads();  // drains vmcnt (B DMA) + lgkmcnt (A writes)
    cur ^= 1;
  }
  COMPUTE_TILE(cur)

#undef STAGE_B
#undef LOAD_A
#undef WRITE_A
#undef COMPUTE_TILE

  // Epilogue. C/D layout (m89-verified): col = lane&15, row = (lane>>4)*4 + reg
#pragma unroll
  for (int i = 0; i < 4; ++i) {
#pragma unroll
    for (int j = 0; j < 4; ++j) {
#pragma unroll
      for (int r = 0; r < 4; ++r) {
        const int row = m0 + wm * 64 + i * 16 + q * 4 + r;
        const int col = n0 + wn * 64 + j * 16 + sid;
        storeC(&C[(size_t)row * 512 + col], acc[i][j][r]);
      }
    }
  }
}

// ---------------------------------------------------------------------------
// Pool + RoPE. One block per (b, chunk j). 256 threads: half 0 handles window
// entries t=0..31 (prev chunk), half 1 handles t=32..63 (current chunk), each
// with an online softmax over 32 entries; the two partials are merged via a
// standard softmax-merge in LDS. Halves the serial exp-chain and doubles the
// resident wave count vs the 128-thread serial version.
// C columns: [0:128)=kv_lo [128:256)=kv_hi [256:384)=g_lo [384:512)=g_hi
// ---------------------------------------------------------------------------
template <typename CT>
__global__ __launch_bounds__(256) void pool_rope_kernel(
    const CT* __restrict__ C,       // [32768][512]
    const float* __restrict__ pb,   // [64][128] fp32
    float* __restrict__ out) {      // [4*256][128] fp32
  const int blk = blockIdx.x;  // b*256 + j
  const int j = blk & 255;
  const int tid = threadIdx.x;
  const int d = tid & 127;     // head-dim column
  const int half = tid >> 7;   // 0: t in [0,32), 1: t in [32,64)

  const size_t base_hi = (size_t)blk * 32 * 512;  // row (b*8192 + j*32)
  const size_t base_lo = base_hi - (size_t)32 * 512;

  float m = -INFINITY, l = 0.f, o = 0.f;
  const int tbase = half * 32;
#pragma unroll 8
  for (int tt = 0; tt < 32; ++tt) {
    float g, kv;
    const float bias = pb[(tbase + tt) * 128 + d];
    if (half == 0) {
      if (j == 0) {
        g = NEG_BIG;
        kv = 0.f;
      } else {
        g = loadC(&C[base_lo + (size_t)tt * 512 + 256 + d]);
        kv = loadC(&C[base_lo + (size_t)tt * 512 + d]);
      }
    } else {
      g = loadC(&C[base_hi + (size_t)tt * 512 + 384 + d]);
      kv = loadC(&C[base_hi + (size_t)tt * 512 + 128 + d]);
    }
    g += bias;
    const float mn = fmaxf(m, g);
    const float s = __expf(m - mn);   // exp(-inf)=0 handles first iter
    const float p = __expf(g - mn);
    l = l * s + p;
    o = o * s + p * kv;
    m = mn;
  }

  __shared__ float sm[128], sl[128], so[128];
  if (half == 1) {
    sm[d] = m;
    sl[d] = l;
    so[d] = o;
  }
  __syncthreads();
  if (half == 0) {
    const float m1 = sm[d], l1 = sl[d], o1 = so[d];
    const float mn = fmaxf(m, m1);
    const float s0 = __expf(m - mn), s1 = __expf(m1 - mn);
    const float L = l * s0 + l1 * s1;
    const float O = o * s0 + o1 * s1;
    const float pooled = O / L;

    float res;
    if (d < 64) {
      res = pooled;  // nope part
    } else {
      const int rho = d - 64;
      const int i2 = rho >> 1;
      const float pos = (float)(j * 32);
      const float inv = powf(10000.0f, -(float)(2 * i2) / 64.0f);
      const float f = pos * inv;
      const float c = cosf(f), s2 = sinf(f);
      const float partner = __shfl_xor(pooled, 1, 64);  // pair within wave
      // out[2i] = x[2i]*c - x[2i+1]*s ; out[2i+1] = x[2i+1]*c + x[2i]*s
      res = (rho & 1) ? (pooled * c + partner * s2) : (pooled * c - partner * s2);
    }
    out[(size_t)blk * 128 + d] = res;
  }
}

// ---------------------------------------------------------------------------
extern "C" void kernel_launch(void* const* d_in, const int* in_sizes, int n_in,
                              void* d_out, int out_size, void* d_ws,
                              size_t ws_size, hipStream_t stream) {
  (void)in_sizes; (void)n_in; (void)out_size;
  const float* hidden = (const float*)d_in[0];  // [4][8192][4096] fp32
  const float* w_kv = (const float*)d_in[1];    // [4096][256] fp32
  const float* w_gate = (const float*)d_in[2];  // [4096][256] fp32
  const float* pb = (const float*)d_in[3];      // [64][128] fp32
  float* out = (float*)d_out;                   // [4][256][128] fp32

  ushort_t* Wt = (ushort_t*)d_ws;  // 512*4096*2 = 4 MiB
  const size_t wt_bytes = (size_t)512 * 4096 * sizeof(ushort_t);
  char* cbase = (char*)d_ws + wt_bytes;
  const size_t c_elems = (size_t)32768 * 512;

  transpose_w_kernel<<<dim3(64, 8), 256, 0, stream>>>(w_kv, w_gate, Wt);

  if (ws_size >= wt_bytes + c_elems * sizeof(float)) {
    float* Cf = (float*)cbase;  // 67 MiB fp32 intermediate
    gemm_kernel<float><<<dim3(1024), 256, 0, stream>>>(hidden, Wt, Cf);
    pool_rope_kernel<float><<<dim3(1024), 256, 0, stream>>>(Cf, pb, out);
  } else {
    ushort_t* Cb = (ushort_t*)cbase;  // 33.5 MiB bf16 fallback
    gemm_kernel<ushort_t><<<dim3(1024), 256, 0, stream>>>(hidden, Wt, Cb);
    pool_rope_kernel<ushort_t><<<dim3(1024), 256, 0, stream>>>(Cb, pb, out);
  }
}

// Round 2
// 829.590 us; speedup vs baseline: 1.1326x; 1.1229x over previous
//
#include <hip/hip_runtime.h>
#include <hip/hip_bf16.h>
#include <math.h>

typedef unsigned short ushort_t;
typedef __bf16 bf16x8 __attribute__((ext_vector_type(8)));
typedef float floatx4 __attribute__((ext_vector_type(4)));
typedef float floatx8 __attribute__((ext_vector_type(8)));

#define NEG_BIG -1000000000.0f

__device__ __forceinline__ float b2f(ushort_t u) {
  union { unsigned int i; float f; } v;
  v.i = ((unsigned int)u) << 16;
  return v.f;
}
__device__ __forceinline__ ushort_t f2b(float f) {
  union { float f; unsigned int i; } v;
  v.f = f;
  unsigned int r = v.i + 0x7fffu + ((v.i >> 16) & 1u);  // round-nearest-even
  return (ushort_t)(r >> 16);
}

__device__ __forceinline__ float loadC(const float* p) { return *p; }
__device__ __forceinline__ float loadC(const ushort_t* p) { return b2f(*p); }
__device__ __forceinline__ void storeC(float* p, float v) { *p = v; }
__device__ __forceinline__ void storeC(ushort_t* p, float v) { *p = f2b(v); }

// ---------------------------------------------------------------------------
// Weight transpose + fp32->bf16 convert: Wt[512][4096] bf16.
// Rows 0..255 = w_kv columns, rows 256..511 = w_gate columns.
// ---------------------------------------------------------------------------
__global__ __launch_bounds__(256) void transpose_w_kernel(
    const float* __restrict__ w_kv, const float* __restrict__ w_gate,
    ushort_t* __restrict__ Wt) {
  __shared__ float tile[64][65];   // +1 pad: conflict-free transposed read
  const int K0 = blockIdx.x * 64;  // grid.x = 64  (K = 4096)
  const int N0c = blockIdx.y * 64; // grid.y = 8   (Ncat = 512)
  const float* src = (N0c < 256) ? w_kv : w_gate;
  const int N0 = N0c & 255;
  const int t = threadIdx.x;
#pragma unroll
  for (int i = 0; i < 16; ++i) {
    int l = t + 256 * i;
    int r = l >> 6, c = l & 63;
    tile[r][c] = src[(size_t)(K0 + r) * 256 + N0 + c];  // coalesced in c
  }
  __syncthreads();
#pragma unroll
  for (int i = 0; i < 16; ++i) {
    int l = t + 256 * i;
    int r = l >> 6, c = l & 63;
    Wt[(size_t)(N0c + r) * 4096 + K0 + c] = f2b(tile[c][r]);  // coalesced in c
  }
}

// ---------------------------------------------------------------------------
// GEMM: C[32768][512] = hidden_f32[32768][4096] @ Wt^T  (Wt is [512][4096] bf16)
// BM=128 x BN=256 tile, BK=64, 512 threads (8 waves, 2x4 grid of 64x64 wave
// tiles). Rationale (round-1 post-mortem): the kernel is bound by beyond-L2
// A-traffic = (#nt siblings) x 537 MB at the ~5.5 TB/s L3/HBM tier. BN=256
// halves the sibling count (4 -> 2) and thus the A re-fetch volume.
// Double-buffered LDS (96 KiB), prefetch-1 schedule, XOR-swizzled tiles
// (conflict-free ds_read_b128, verified 0 conflicts in round 1), bijective
// XCD block swizzle (512 blocks % 8 == 0) keeps nt-siblings on one XCD.
// ---------------------------------------------------------------------------
template <typename CT>
__global__ __launch_bounds__(512, 2) void gemm_kernel(
    const float* __restrict__ A,      // [32768][4096] fp32
    const ushort_t* __restrict__ Bt,  // [512][4096] bf16
    CT* __restrict__ C) {             // [32768][512]
  constexpr int K = 4096;
  __shared__ __align__(16) ushort_t As[2][128 * 64];  // 2 x 16 KiB
  __shared__ __align__(16) ushort_t Bs[2][256 * 64];  // 2 x 32 KiB

  // XCD-aware bijective swizzle: nwg=512, cpx=64. nt fast-varying so the 2
  // blocks sharing an A-panel are adjacent (same XCD, adjacent CUs).
  const int bid = blockIdx.x;
  const int o = (bid & 7) * 64 + (bid >> 3);
  const int mt = o >> 1;           // 256 m-tiles
  const int nt = o & 1;            // 2 n-tiles
  const int m0 = mt * 128, n0 = nt * 256;

  const int tid = threadIdx.x;
  const int w = tid >> 6, lane = tid & 63;
  const int wm = w >> 2, wn = w & 3;   // 2x4 wave grid, 64x64 each
  const int q = lane >> 4, sid = lane & 15;
  // B staging: lane covers (row-sub lane>>3, k-chunk lane&7) of an 8-row chunk.
  // LDS dest is linear; fetch the inverse-swizzled global chunk so LDS slot
  // (row, c) holds global chunk c ^ (row&7).
  const int bsr = lane >> 3;                      // row within 8-row chunk
  const int bsc = ((lane & 7) ^ bsr) * 8;         // swizzled global k-offset
  // A staging (reg-staged fp32->bf16): write to swizzled LDS slot directly.
  const int ar = tid >> 3;                        // 0..63 row within pass
  const int aca = tid & 7;                        // global k-chunk 0..7
  const int acs = (aca ^ (ar & 7)) * 8;           // swizzled LDS k-offset

  floatx4 acc[4][4];
#pragma unroll
  for (int i = 0; i < 4; ++i)
#pragma unroll
    for (int j = 0; j < 4; ++j) acc[i][j] = (floatx4)0.0f;

#define STAGE_B(BUF, KT)                                                      \
  _Pragma("unroll")                                                           \
  for (int i = 0; i < 4; ++i) {                                               \
    const int chunk = i * 8 + w; /* 32 chunks x 8 rows = 256 rows */          \
    const int row = chunk * 8 + bsr;                                          \
    const ushort_t* g = Bt + (size_t)(n0 + row) * K + (KT) + bsc;             \
    __builtin_amdgcn_global_load_lds(                                         \
        (const __attribute__((address_space(1))) void*)g,                     \
        (__attribute__((address_space(3))) void*)(&Bs[BUF][chunk * 512]), 16, \
        0, 0);                                                                \
  }

#define LOAD_A(KT, FREG)                                                      \
  _Pragma("unroll")                                                           \
  for (int p = 0; p < 2; ++p) {                                               \
    const int row = p * 64 + ar;                                              \
    FREG[p] = *(const floatx8*)(A + (size_t)(m0 + row) * K + (KT) + aca * 8); \
  }

#define WRITE_A(BUF, FREG)                                                    \
  _Pragma("unroll")                                                           \
  for (int p = 0; p < 2; ++p) {                                               \
    const int row = p * 64 + ar;                                              \
    *(bf16x8*)(&As[BUF][row * 64 + acs]) =                                    \
        __builtin_convertvector(FREG[p], bf16x8);                             \
  }

#define COMPUTE_TILE(BUF)                                                     \
  _Pragma("unroll")                                                           \
  for (int ks = 0; ks < 64; ks += 32) {                                       \
    const int kc = ks >> 3; /* 0 or 4 */                                      \
    bf16x8 af[4], bfr[4];                                                     \
    _Pragma("unroll")                                                         \
    for (int i = 0; i < 4; ++i) {                                             \
      const int ra = wm * 64 + i * 16 + sid;                                  \
      af[i] =                                                                 \
          *(const bf16x8*)(&As[BUF][ra * 64 + ((kc + q) ^ (sid & 7)) * 8]);   \
    }                                                                         \
    _Pragma("unroll")                                                         \
    for (int j2 = 0; j2 < 4; ++j2) {                                          \
      const int rb = wn * 64 + j2 * 16 + sid;                                 \
      bfr[j2] =                                                               \
          *(const bf16x8*)(&Bs[BUF][rb * 64 + ((kc + q) ^ (sid & 7)) * 8]);   \
    }                                                                         \
    _Pragma("unroll")                                                         \
    for (int i = 0; i < 4; ++i)                                               \
      _Pragma("unroll")                                                       \
      for (int j2 = 0; j2 < 4; ++j2)                                          \
        acc[i][j2] = __builtin_amdgcn_mfma_f32_16x16x32_bf16(                 \
            af[i], bfr[j2], acc[i][j2], 0, 0, 0);                             \
  }

  // ---- prologue: stage tile kt=0 into buffer 0
  {
    STAGE_B(0, 0)
    floatx8 f[2];
    LOAD_A(0, f)
    WRITE_A(0, f)
  }
  __syncthreads();

  int cur = 0;
  for (int kt = 64; kt < K; kt += 64) {
    // issue next-tile loads first: A -> regs, B -> LDS[cur^1] (async DMA)
    floatx8 f[2];
    LOAD_A(kt, f)
    STAGE_B(cur ^ 1, kt)
    // compute current tile while loads are in flight
    COMPUTE_TILE(cur)
    // convert + write prefetched A (compiler inserts the vmcnt wait here)
    WRITE_A(cur ^ 1, f)
    __syncthreads();  // drains vmcnt (B DMA) + lgkmcnt (A writes)
    cur ^= 1;
  }
  COMPUTE_TILE(cur)

#undef STAGE_B
#undef LOAD_A
#undef WRITE_A
#undef COMPUTE_TILE

  // Epilogue. C/D layout (m89-verified): col = lane&15, row = (lane>>4)*4 + reg
#pragma unroll
  for (int i = 0; i < 4; ++i) {
#pragma unroll
    for (int j = 0; j < 4; ++j) {
#pragma unroll
      for (int r = 0; r < 4; ++r) {
        const int row = m0 + wm * 64 + i * 16 + q * 4 + r;
        const int col = n0 + wn * 64 + j * 16 + sid;
        storeC(&C[(size_t)row * 512 + col], acc[i][j][r]);
      }
    }
  }
}

// ---------------------------------------------------------------------------
// Pool + RoPE. One block per (b, chunk j). 256 threads: half 0 handles window
// entries t=0..31 (prev chunk), half 1 handles t=32..63 (current chunk), each
// with an online softmax over 32 entries; partials merged via LDS.
// C columns: [0:128)=kv_lo [128:256)=kv_hi [256:384)=g_lo [384:512)=g_hi
// ---------------------------------------------------------------------------
template <typename CT>
__global__ __launch_bounds__(256) void pool_rope_kernel(
    const CT* __restrict__ C,       // [32768][512]
    const float* __restrict__ pb,   // [64][128] fp32
    float* __restrict__ out) {      // [4*256][128] fp32
  const int blk = blockIdx.x;  // b*256 + j
  const int j = blk & 255;
  const int tid = threadIdx.x;
  const int d = tid & 127;     // head-dim column
  const int half = tid >> 7;   // 0: t in [0,32), 1: t in [32,64)

  const size_t base_hi = (size_t)blk * 32 * 512;  // row (b*8192 + j*32)
  const size_t base_lo = base_hi - (size_t)32 * 512;

  float m = -INFINITY, l = 0.f, o = 0.f;
  const int tbase = half * 32;
#pragma unroll 8
  for (int tt = 0; tt < 32; ++tt) {
    float g, kv;
    const float bias = pb[(tbase + tt) * 128 + d];
    if (half == 0) {
      if (j == 0) {
        g = NEG_BIG;
        kv = 0.f;
      } else {
        g = loadC(&C[base_lo + (size_t)tt * 512 + 256 + d]);
        kv = loadC(&C[base_lo + (size_t)tt * 512 + d]);
      }
    } else {
      g = loadC(&C[base_hi + (size_t)tt * 512 + 384 + d]);
      kv = loadC(&C[base_hi + (size_t)tt * 512 + 128 + d]);
    }
    g += bias;
    const float mn = fmaxf(m, g);
    const float s = __expf(m - mn);   // exp(-inf)=0 handles first iter
    const float p = __expf(g - mn);
    l = l * s + p;
    o = o * s + p * kv;
    m = mn;
  }

  __shared__ float sm[128], sl[128], so[128];
  if (half == 1) {
    sm[d] = m;
    sl[d] = l;
    so[d] = o;
  }
  __syncthreads();
  if (half == 0) {
    const float m1 = sm[d], l1 = sl[d], o1 = so[d];
    const float mn = fmaxf(m, m1);
    const float s0 = __expf(m - mn), s1 = __expf(m1 - mn);
    const float L = l * s0 + l1 * s1;
    const float O = o * s0 + o1 * s1;
    const float pooled = O / L;

    float res;
    if (d < 64) {
      res = pooled;  // nope part
    } else {
      const int rho = d - 64;
      const int i2 = rho >> 1;
      const float pos = (float)(j * 32);
      const float inv = powf(10000.0f, -(float)(2 * i2) / 64.0f);
      const float f = pos * inv;
      const float c = cosf(f), s2 = sinf(f);
      const float partner = __shfl_xor(pooled, 1, 64);  // pair within wave
      // out[2i] = x[2i]*c - x[2i+1]*s ; out[2i+1] = x[2i+1]*c + x[2i]*s
      res = (rho & 1) ? (pooled * c + partner * s2) : (pooled * c - partner * s2);
    }
    out[(size_t)blk * 128 + d] = res;
  }
}

// ---------------------------------------------------------------------------
extern "C" void kernel_launch(void* const* d_in, const int* in_sizes, int n_in,
                              void* d_out, int out_size, void* d_ws,
                              size_t ws_size, hipStream_t stream) {
  (void)in_sizes; (void)n_in; (void)out_size;
  const float* hidden = (const float*)d_in[0];  // [4][8192][4096] fp32
  const float* w_kv = (const float*)d_in[1];    // [4096][256] fp32
  const float* w_gate = (const float*)d_in[2];  // [4096][256] fp32
  const float* pb = (const float*)d_in[3];      // [64][128] fp32
  float* out = (float*)d_out;                   // [4][256][128] fp32

  ushort_t* Wt = (ushort_t*)d_ws;  // 512*4096*2 = 4 MiB
  const size_t wt_bytes = (size_t)512 * 4096 * sizeof(ushort_t);
  char* cbase = (char*)d_ws + wt_bytes;
  const size_t c_elems = (size_t)32768 * 512;

  transpose_w_kernel<<<dim3(64, 8), 256, 0, stream>>>(w_kv, w_gate, Wt);

  if (ws_size >= wt_bytes + c_elems * sizeof(float)) {
    float* Cf = (float*)cbase;  // 67 MiB fp32 intermediate
    gemm_kernel<float><<<dim3(512), 512, 0, stream>>>(hidden, Wt, Cf);
    pool_rope_kernel<float><<<dim3(1024), 256, 0, stream>>>(Cf, pb, out);
  } else {
    ushort_t* Cb = (ushort_t*)cbase;  // 33.5 MiB bf16 fallback
    gemm_kernel<ushort_t><<<dim3(512), 512, 0, stream>>>(hidden, Wt, Cb);
    pool_rope_kernel<ushort_t><<<dim3(1024), 256, 0, stream>>>(Cb, pb, out);
  }
}